// Round 7
// baseline (1872.336 us; speedup 1.0000x reference)
//
#include <hip/hip_runtime.h>
#include <hip/hip_bf16.h>

// CTRNN on MI355X — single fused kernel.
//   out layout (fp32): output[512][128][1024] | hidden[128][1024] | ip[512][128][1024]
// Blocks 0..127   : persistent recurrent blocks (8 batch-tiles x 16 H-tiles),
//                   W_hh slice in VGPRs, K-split across 4 waves, h exchanged via
//                   depth-2 sc0+sc1 ring + per-WAVE 16B-padded flags.
// Blocks 128..+16383 : ip tiles (64x64, K=512) computing ip = x@W_in^T + b_in,
//                   W_in converted inline, sc0+sc1 stores (write-through so rec's
//                   first-touch cached reads are fresh), per-t completion counter.
// 84KB static LDS forces 1 block/CU: ip blocks can't co-tenant rec CUs.

typedef __attribute__((ext_vector_type(8))) short short8;
typedef __attribute__((ext_vector_type(4))) float f32x4;

#define S_LEN 512
#define BATCH 128
#define IN_DIM 512
#define HID 1024
#define NREC 128
#define IP_TILES 16384   // (65536/64) M-tiles * (1024/64) N-tiles

__device__ __forceinline__ ushort f2bf(float f) {
    __hip_bfloat16 h = __float2bfloat16(f);
    return *reinterpret_cast<ushort*>(&h);
}

__global__ __launch_bounds__(256, 1) void ctrnn_fused(
        const float* __restrict__ x, const float* __restrict__ W_in,
        const float* __restrict__ b_in, const float* __restrict__ whh,
        const float* __restrict__ b_hh, float* __restrict__ out,
        float* __restrict__ hidden, float* __restrict__ ip,
        ushort* __restrict__ hbuf, int* __restrict__ flags,
        int* __restrict__ flags_ip) {
    __shared__ __align__(16) char lds_raw[84 * 1024];
    const int tid  = threadIdx.x;
    const int lane = tid & 63;
    const int w    = tid >> 6;

    if (blockIdx.x >= NREC) {
        // ======================= ip tile =======================
        ushort* As = (ushort*)lds_raw;
        ushort* Bs = (ushort*)(lds_raw + 4096);
        const int bid = blockIdx.x - NREC;
        const int mt  = bid >> 4;          // ascending t with blockIdx
        const int nt  = bid & 15;
        const long Mbase = (long)mt * 64;
        const int  Nbase = nt * 64;
        const int sr = tid >> 2;
        const int sk = (tid & 3) * 8;

        f32x4 acc0 = {0,0,0,0}, acc1 = {0,0,0,0}, acc2 = {0,0,0,0}, acc3 = {0,0,0,0};
        const int ar   = w * 16 + (lane & 15);
        const int kb   = ((lane >> 4) * 8) * 2;
        const int aoff = (ar * 64 + kb) ^ ((ar & 7) << 4);
        const int boff = ((lane & 15) * 64 + kb) ^ (((lane & 15) & 7) << 4);
        const int soff = (sr * 64 + sk * 2) ^ ((sr & 7) << 4);

        for (int kc = 0; kc < IN_DIM; kc += 32) {
            const float* apg = x + (Mbase + sr) * IN_DIM + kc + sk;
            f32x4 av0 = *(const f32x4*)apg;
            f32x4 av1 = *(const f32x4*)(apg + 4);
            const float* wpg = W_in + (size_t)(Nbase + sr) * IN_DIM + kc + sk;
            f32x4 bv0 = *(const f32x4*)wpg;
            f32x4 bv1 = *(const f32x4*)(wpg + 4);
            short8 av, bv;
#pragma unroll
            for (int j = 0; j < 4; ++j) {
                av[j]     = (short)f2bf(av0[j]);
                av[4 + j] = (short)f2bf(av1[j]);
                bv[j]     = (short)f2bf(bv0[j]);
                bv[4 + j] = (short)f2bf(bv1[j]);
            }
            __syncthreads();
            *(short8*)((char*)As + soff) = av;
            *(short8*)((char*)Bs + soff) = bv;
            __syncthreads();

            short8 a  = *(const short8*)((char*)As + aoff);
            short8 b0 = *(const short8*)((char*)Bs + boff);
            short8 b1 = *(const short8*)((char*)Bs + boff + 1024);
            short8 b2 = *(const short8*)((char*)Bs + boff + 2048);
            short8 b3 = *(const short8*)((char*)Bs + boff + 3072);
            acc0 = __builtin_amdgcn_mfma_f32_16x16x32_bf16(a, b0, acc0, 0, 0, 0);
            acc1 = __builtin_amdgcn_mfma_f32_16x16x32_bf16(a, b1, acc1, 0, 0, 0);
            acc2 = __builtin_amdgcn_mfma_f32_16x16x32_bf16(a, b2, acc2, 0, 0, 0);
            acc3 = __builtin_amdgcn_mfma_f32_16x16x32_bf16(a, b3, acc3, 0, 0, 0);
        }

        const int nl   = lane & 15;
        const int mrow = w * 16 + (lane >> 4) * 4;
        const float bi0 = b_in[Nbase + nl];
        const float bi1 = b_in[Nbase + 16 + nl];
        const float bi2 = b_in[Nbase + 32 + nl];
        const float bi3 = b_in[Nbase + 48 + nl];
#pragma unroll
        for (int j = 0; j < 4; ++j) {
            float* op = ip + (Mbase + mrow + j) * HID + Nbase + nl;
            float v0 = acc0[j] + bi0, v1 = acc1[j] + bi1;
            float v2 = acc2[j] + bi2, v3 = acc3[j] + bi3;
            asm volatile("global_store_dword %0, %1, off sc0 sc1" :: "v"(op),      "v"(v0) : "memory");
            asm volatile("global_store_dword %0, %1, off sc0 sc1" :: "v"(op + 16), "v"(v1) : "memory");
            asm volatile("global_store_dword %0, %1, off sc0 sc1" :: "v"(op + 32), "v"(v2) : "memory");
            asm volatile("global_store_dword %0, %1, off sc0 sc1" :: "v"(op + 48), "v"(v3) : "memory");
        }
        asm volatile("s_waitcnt vmcnt(0)" ::: "memory");
        __syncthreads();
        if (tid == 0) atomicAdd(&flags_ip[mt >> 1], 1);   // 32 tiles per t
        return;
    }

    // ======================= recurrent block =======================
    float* P = (float*)lds_raw;   // [4][16][68] K-partials, padded
    const int bi = blockIdx.x & 7;
    const int ni = blockIdx.x >> 3;
    const int arow = lane & 15;
    const int kgrp = (lane >> 4) * 8;

    // W_hh fragments: wf[g][kk] = W[ni*64+g*16+arow][w*256 + kk*32 + kgrp + 0..7]
    short8 wf[4][8];
#pragma unroll
    for (int g = 0; g < 4; ++g)
#pragma unroll
        for (int kk = 0; kk < 8; ++kk) {
            const float* wp = whh + (size_t)(ni * 64 + g * 16 + arow) * HID
                              + w * 256 + kk * 32 + kgrp;
            f32x4 w0 = *(const f32x4*)wp;
            f32x4 w1 = *(const f32x4*)(wp + 4);
            short8 f;
#pragma unroll
            for (int j = 0; j < 4; ++j) {
                f[j]     = (short)f2bf(w0[j]);
                f[4 + j] = (short)f2bf(w1[j]);
            }
            wf[g][kk] = f;
        }

    const int eb = tid >> 4;
    const int n0 = (tid & 15) * 4;
    const f32x4 bias4 = *(const f32x4*)&b_hh[ni * 64 + n0];
    f32x4 hprev = {0, 0, 0, 0};

    // ---- wait for ip[t=0] (32 tiles), then load first xt ----
    {
        const int* fip = flags_ip;
        long spin = 0;
        for (;;) {
            int v;
            asm volatile("global_load_dword %0, %1, off sc0 sc1\n\ts_waitcnt vmcnt(0)"
                         : "=v"(v) : "v"(fip) : "memory");
            if (__all(v >= 32)) break;
            if (++spin > (1L << 22)) break;
        }
    }
    f32x4 xtv = *(const f32x4*)&ip[(size_t)(bi * 16 + eb) * HID + ni * 64 + n0];

    for (int t = 0; t < S_LEN; ++t) {
        f32x4 acc = {0, 0, 0, 0};
        if (t > 0) {
            // ---- poll 16 producer-wave flags (4 blocks x 4 waves), lanes 0-15 ----
            if (lane < 16) {
                const int* fl = flags + (((size_t)(t - 1) * 8 + bi) * 64 + w * 16 + lane) * 4;
                long spin = 0;
                for (;;) {
                    int v;
                    asm volatile("global_load_dword %0, %1, off sc0 sc1\n\ts_waitcnt vmcnt(0)"
                                 : "=v"(v) : "v"(fl) : "memory");
                    if (__all(v != 0)) break;
                    if (++spin > (1L << 22)) break;
                }
            }

            // ---- load A-frags directly from global (2 KB per wave) ----
            const ushort* hs = hbuf + (size_t)((t - 1) & 1) * BATCH * HID
                               + (size_t)(bi * 16 + arow) * HID + w * 256 + kgrp;
            short8 af0, af1, af2, af3, af4, af5, af6, af7;
#define LDA(reg, kk)                                                            \
            asm volatile("global_load_dwordx4 %0, %1, off sc0 sc1"              \
                         : "=v"(reg) : "v"(hs + (kk) * 32) : "memory")
            LDA(af0, 0); LDA(af1, 1); LDA(af2, 2); LDA(af3, 3);
            LDA(af4, 4); LDA(af5, 5); LDA(af6, 6); LDA(af7, 7);
#undef LDA
            asm volatile("s_waitcnt vmcnt(0)" ::: "memory");
            __builtin_amdgcn_sched_barrier(0);

            // ---- 32 MFMAs: 4 n-groups x 8 k-chunks (K-partials) ----
            f32x4 a0 = {0,0,0,0}, a1 = {0,0,0,0}, a2 = {0,0,0,0}, a3 = {0,0,0,0};
#define STEP(afk, kk)                                                               \
            a0 = __builtin_amdgcn_mfma_f32_16x16x32_bf16(afk, wf[0][kk], a0, 0, 0, 0); \
            a1 = __builtin_amdgcn_mfma_f32_16x16x32_bf16(afk, wf[1][kk], a1, 0, 0, 0); \
            a2 = __builtin_amdgcn_mfma_f32_16x16x32_bf16(afk, wf[2][kk], a2, 0, 0, 0); \
            a3 = __builtin_amdgcn_mfma_f32_16x16x32_bf16(afk, wf[3][kk], a3, 0, 0, 0)
            STEP(af0, 0); STEP(af1, 1); STEP(af2, 2); STEP(af3, 3);
            STEP(af4, 4); STEP(af5, 5); STEP(af6, 6); STEP(af7, 7);
#undef STEP

            // ---- write K-partials (C/D map: row=(lane>>4)*4+j, col=arow) ----
#pragma unroll
            for (int j = 0; j < 4; ++j) {
                const int br = (lane >> 4) * 4 + j;
                float* Pr = P + w * 1088 + br * 68;
                Pr[arow]      = a0[j];
                Pr[16 + arow] = a1[j];
                Pr[32 + arow] = a2[j];
                Pr[48 + arow] = a3[j];
            }
            __syncthreads();

            // ---- reduce 4 wave-partials for (eb, n0..n0+3) ----
            f32x4 r0 = *(const f32x4*)(P + 0 * 1088 + eb * 68 + n0);
            f32x4 r1 = *(const f32x4*)(P + 1 * 1088 + eb * 68 + n0);
            f32x4 r2 = *(const f32x4*)(P + 2 * 1088 + eb * 68 + n0);
            f32x4 r3 = *(const f32x4*)(P + 3 * 1088 + eb * 68 + n0);
            acc = (r0 + r1) + (r2 + r3);
        }

        // ---- epilogue: hnew = relu(xt + Wh + b); h = 0.8h + 0.2hnew ----
        f32x4 hw;
#pragma unroll
        for (int j = 0; j < 4; ++j) {
            float hn = xtv[j] + acc[j] + bias4[j];
            hn       = hn > 0.0f ? hn : 0.0f;
            hw[j]    = hprev[j] * 0.8f + 0.2f * hn;
        }
        hprev = hw;

        // ---- publish 8B bf16 -> per-wave drain -> per-wave flag (no barrier) ----
        uint2 pk;
        pk.x = (uint)f2bf(hw[0]) | ((uint)f2bf(hw[1]) << 16);
        pk.y = (uint)f2bf(hw[2]) | ((uint)f2bf(hw[3]) << 16);
        ushort* hdst = hbuf + (size_t)(t & 1) * BATCH * HID
                       + (size_t)(bi * 16 + eb) * HID + ni * 64 + n0;
        asm volatile("global_store_dwordx2 %0, %1, off sc0 sc1" :: "v"(hdst), "v"(pk) : "memory");
        asm volatile("s_waitcnt vmcnt(0)" ::: "memory");
        if (lane == 0) {
            int one = 1;
            int* fdst = flags + (((size_t)t * 8 + bi) * 64 + ni * 4 + w) * 4;
            asm volatile("global_store_dword %0, %1, off sc0 sc1" :: "v"(fdst), "v"(one) : "memory");
        }

        // ---- off-critical-path: out/hidden stores ----
        float* od = out + (size_t)t * BATCH * HID + (size_t)(bi * 16 + eb) * HID + ni * 64 + n0;
        *(f32x4*)od = hw;
        if (t == S_LEN - 1) {
            float* hd = hidden + (size_t)(bi * 16 + eb) * HID + ni * 64 + n0;
            *(f32x4*)hd = hw;
        }

        // ---- prefetch next xt, gated on ip progress (hits immediately post-warmup) ----
        if (t + 1 < S_LEN) {
            const int* fip = flags_ip + (t + 1);
            long spin = 0;
            for (;;) {
                int v;
                asm volatile("global_load_dword %0, %1, off sc0 sc1\n\ts_waitcnt vmcnt(0)"
                             : "=v"(v) : "v"(fip) : "memory");
                if (__all(v >= 32)) break;
                if (++spin > (1L << 22)) break;
            }
            xtv = *(const f32x4*)&ip[(size_t)(t + 1) * BATCH * HID
                                     + (size_t)(bi * 16 + eb) * HID + ni * 64 + n0];
        }
    }
}

extern "C" void kernel_launch(void* const* d_in, const int* in_sizes, int n_in,
                              void* d_out, int out_size, void* d_ws, size_t ws_size,
                              hipStream_t stream) {
    const float* x    = (const float*)d_in[0];
    const float* W_in = (const float*)d_in[1];
    const float* b_in = (const float*)d_in[2];
    const float* W_hh = (const float*)d_in[3];
    const float* b_hh = (const float*)d_in[4];

    float* out    = (float*)d_out;
    float* hidden = out + (size_t)S_LEN * BATCH * HID;
    float* ip     = hidden + (size_t)BATCH * HID;

    char* ws = (char*)d_ws;
    ushort* hbuf     = (ushort*)ws;                              // 512 KB h ring
    int*    flags_ip = (int*)(ws + 768 * 1024);                  // 2 KB per-t counters
    int*    flags    = (int*)(ws + (size_t)1024 * 1024);         // 4 MB wave flags (16B pad)

    hipMemsetAsync(flags_ip, 0, S_LEN * sizeof(int), stream);
    hipMemsetAsync(flags, 0, (size_t)S_LEN * 8 * 64 * 4 * sizeof(int), stream);
    ctrnn_fused<<<NREC + IP_TILES, 256, 0, stream>>>(x, W_in, b_in, W_hh, b_hh,
                                                     out, hidden, ip, hbuf, flags, flags_ip);
}